// Round 9
// baseline (410.776 us; speedup 1.0000x reference)
//
#include <hip/hip_runtime.h>

#define NV  20000
#define NNB 12
#define VC  4            // vertices per block
#define GRID (NV/VC)     // 5000

// ---- LDS float offsets ----
#define OFF_Q    0       // [(v*4+h)*8 + i]      128
#define OFF_F    128     // [vn*132 + c*8 + j]  6336 (live P1..P4-G)
#define OFF_HEAD 128     // [v*520 + hc*8 + i]  2080 (overlays dead F)
#define OFF_SC   6464    // [vn*4 + h] scores -> attn (192)
#define SMEM_FL  6656    // 26624 B = 26 KiB -> 6 blocks/CU

#define LD8(dst, off) { const float4 _a = *(const float4*)&smem[(off)]; \
                        const float4 _b = *(const float4*)&smem[(off)+4]; \
                        dst[0]=_a.x; dst[1]=_a.y; dst[2]=_a.z; dst[3]=_a.w; \
                        dst[4]=_b.x; dst[5]=_b.y; dst[6]=_b.z; dst[7]=_b.w; }
#define ST8(off, src) { *(float4*)&smem[(off)]   = make_float4(src[0],src[1],src[2],src[3]); \
                        *(float4*)&smem[(off)+4] = make_float4(src[4],src[5],src[6],src[7]); }

// ---------------------------------------------------------------------------
// kprep: blocks 0..95 build A4; block 96 = single-writer mask-dtype detect
// (no memset / atomic-init needed). A4[((p*8+i)*64+hc)*8+j] = A(h,c,i,j,p).
// ---------------------------------------------------------------------------
__global__ __launch_bounds__(256) void kprep(
    const float* __restrict__ v0p, const float* __restrict__ v1p,
    const float* __restrict__ v2p, const float* __restrict__ vb1,
    const float* __restrict__ vb2, float* __restrict__ A4,
    const unsigned char* __restrict__ m, int* __restrict__ flag)
{
    const int b = blockIdx.x, tid = threadIdx.x;
    if (b < 96) {
        int idx = b * 256 + tid;
        int j = idx & 7;
        int t = idx >> 3;
        int hc = t & 63; t >>= 6;
        int i = t & 7;
        int p = t >> 3;
        int h = hc >> 4, c = hc & 15;
        float s = 0.f;
        if (p == 0) {
            s = v0p[h*128 + c*8 + ((j - i + 8) & 7)];
        } else if (p <= 2) {
            int o = p - 1;
            #pragma unroll
            for (int bb = 0; bb < 8; ++bb)
                s += v1p[h*128 + c*8 + bb] * vb1[((bb*2 + o)*8 + i)*8 + j];
        } else {
            int o = p - 3;
            #pragma unroll
            for (int bb = 0; bb < 8; ++bb)
                s += v2p[h*128 + c*8 + bb] * vb2[((bb*3 + o)*8 + i)*8 + j];
        }
        A4[idx] = s;
    } else {
        // Detect: any nonzero byte at offset%4!=0 within the mask words
        // => byte(bool) storage. int32 storage (0/1) has all such bytes zero.
        __shared__ int s_nz;
        if (tid == 0) s_nz = 0;
        __syncthreads();
        const int4* mi4 = (const int4*)m;
        int nz = 0;
        for (int k = tid; k < (NV*NNB)/16; k += 256) {
            int4 w = mi4[k];
            nz |= (w.x | w.y | w.z | w.w) & 0xFFFFFF00;
        }
        if (nz) atomicOr(&s_nz, 1);
        __syncthreads();
        if (tid == 0) flag[0] = (s_nz != 0) ? 1 : 0;
    }
}

// ---------------------------------------------------------------------------
// Fused main: 4 vertices/block, 6 barriers, 26624 B LDS, all phases full-width.
// ---------------------------------------------------------------------------
__global__ __launch_bounds__(256, 6) void kmain(
    const float* __restrict__ x, const int* __restrict__ nbr,
    const unsigned char* __restrict__ mskb, const float* __restrict__ pt,
    const float* __restrict__ rel, const float* __restrict__ qc,
    const float* __restrict__ kc, const float* __restrict__ A4,
    const float* __restrict__ wm, const int* __restrict__ flagp,
    float* __restrict__ out)
{
    const int tid = threadIdx.x;
    const int vbase = blockIdx.x * VC;
    const int bytemode = flagp[0];
    const int* mski = (const int*)mskb;

    __shared__ __align__(16) float smem[SMEM_FL];

    // ---- P1: [0..191] f ; [192..255] Q (concurrent) ----
    if (tid < 192) {
        const int vn = tid >> 2, cq = tid & 3;
        const int gi = vbase*NNB + vn;
        const int nb = nbr[gi];
        const float m = (bytemode ? (int)mskb[gi] : mski[gi]) ? 1.0f : 0.0f;
        const float4* xg = (const float4*)(x + (size_t)nb*128 + cq*32);
        const float* ptg = pt + (size_t)gi*64;
        #pragma unroll
        for (int cp2 = 0; cp2 < 2; ++cp2) {
            const float4 xa0 = xg[cp2*4+0], xb0 = xg[cp2*4+1];
            const float4 xa1 = xg[cp2*4+2], xb1 = xg[cp2*4+3];
            float a0[8], a1[8];
            #pragma unroll
            for (int i = 0; i < 8; ++i) {
                const float4 pA = *(const float4*)(ptg + i*8);
                const float4 pB = *(const float4*)(ptg + i*8 + 4);
                a0[i] = pA.x*xa0.x + pA.y*xa0.y + pA.z*xa0.z + pA.w*xa0.w
                      + pB.x*xb0.x + pB.y*xb0.y + pB.z*xb0.z + pB.w*xb0.w;
                a1[i] = pA.x*xa1.x + pA.y*xa1.y + pA.z*xa1.z + pA.w*xa1.w
                      + pB.x*xb1.x + pB.y*xb1.y + pB.z*xb1.z + pB.w*xb1.w;
            }
            const int c0 = cq*4 + cp2*2;
            float w0[8], w1[8];
            #pragma unroll
            for (int i = 0; i < 8; ++i) { w0[i] = m*a0[i]; w1[i] = m*a1[i]; }
            ST8(OFF_F + vn*132 + c0*8, w0);
            ST8(OFF_F + vn*132 + (c0+1)*8, w1);
        }
    } else {
        const int t = tid - 192, v = t >> 4, h = (t >> 2) & 3, cs = t & 3;
        const float* xrow = x + (size_t)(vbase + v)*128;
        const float* qcb  = qc + h*128;
        float Q8[8] = {0,0,0,0,0,0,0,0};
        #pragma unroll
        for (int q = 0; q < 4; ++q) {
            const int c = cs*4 + q;
            const float4 xa = *(const float4*)(xrow + c*8);
            const float4 xb = *(const float4*)(xrow + c*8 + 4);
            const float4 qa = *(const float4*)(qcb + c*8);
            const float4 qb = *(const float4*)(qcb + c*8 + 4);
            float xv[8] = {xa.x,xa.y,xa.z,xa.w,xb.x,xb.y,xb.z,xb.w};
            float qv[8] = {qa.x,qa.y,qa.z,qa.w,qb.x,qb.y,qb.z,qb.w};
            #pragma unroll
            for (int s = 0; s < 8; ++s)
                #pragma unroll
                for (int i = 0; i < 8; ++i)
                    Q8[i] += qv[s] * xv[(i+s)&7];
        }
        #pragma unroll
        for (int i = 0; i < 8; ++i) {
            Q8[i] += __shfl_xor(Q8[i], 1, 64);
            Q8[i] += __shfl_xor(Q8[i], 2, 64);
        }
        if (cs == 0) { ST8(OFF_Q + (v*4+h)*8, Q8); }
    }
    __syncthreads();

    // ---- P2: K + scores (kc from global/L1) ----
    if (tid < 192) {
        const int vn = tid >> 2, h = tid & 3, v = vn / 12;
        const float* kcb = kc + h*128;
        float K8[8] = {0,0,0,0,0,0,0,0};
        #pragma unroll 2
        for (int c = 0; c < 16; ++c) {
            const float4 ka = *(const float4*)(kcb + c*8);
            const float4 kb = *(const float4*)(kcb + c*8 + 4);
            float kv[8] = {ka.x,ka.y,ka.z,ka.w,kb.x,kb.y,kb.z,kb.w};
            float fv[8]; LD8(fv, OFF_F + vn*132 + c*8);
            #pragma unroll
            for (int s = 0; s < 8; ++s)
                #pragma unroll
                for (int i = 0; i < 8; ++i)
                    K8[i] += kv[s] * fv[(i+s)&7];
        }
        float q8[8]; LD8(q8, OFF_Q + (v*4+h)*8);
        const int gi = vbase*NNB + vn;
        const float m = (bytemode ? (int)mskb[gi] : mski[gi]) ? 1.0f : 0.0f;
        float s = 0.f;
        #pragma unroll
        for (int i = 0; i < 8; ++i) s += fmaxf(0.f, q8[i] + K8[i]);
        smem[OFF_SC + vn*4 + h] = 0.125f * s * m;
    }
    __syncthreads();

    // ---- P3: attn (den recomputed per-thread; snapshot then write) ----
    float at = 0.f;
    if (tid < 192) {
        const int vn = tid >> 2, h = tid & 3, v = vn / 12, nb0 = v*12;
        float den = 0.f;
        #pragma unroll
        for (int n = 0; n < 12; ++n) den += smem[OFF_SC + (nb0+n)*4 + h];
        float nv = 0.f;
        #pragma unroll
        for (int n = 0; n < 12; ++n) {
            const int gi = vbase*NNB + nb0 + n;
            nv += (bytemode ? (int)mskb[gi] : mski[gi]) ? 1.0f : 0.0f;
        }
        const int gi = vbase*NNB + vn;
        const float m = (bytemode ? (int)mskb[gi] : mski[gi]) ? 1.0f : 0.0f;
        const float sc = smem[OFF_SC + vn*4 + h];
        at = (den < 1e-6f) ? (m / fmaxf(nv, 1.0f)) : (sc / fmaxf(den, 1e-6f));
    }
    __syncthreads();
    if (tid < 192) smem[OFF_SC + (tid >> 2)*4 + (tid & 3)] = at;
    __syncthreads();

    // ---- P4: G (regs) then head (A4 streamed from L2) ----
    const int v4 = tid >> 6, h4 = (tid >> 4) & 3, c4 = tid & 15, hc = tid & 63;
    float G[6][8];
    #pragma unroll
    for (int p = 0; p < 6; ++p)
        #pragma unroll
        for (int j = 0; j < 8; ++j) G[p][j] = 0.f;
    const int gbase = vbase*NNB + v4*12;
    for (int n = 0; n < 12; ++n) {
        const int vn = v4*12 + n;
        const float a = smem[OFF_SC + vn*4 + h4];
        const float2 uv = *(const float2*)(rel + (size_t)(gbase + n)*2);
        float fv[8]; LD8(fv, OFF_F + vn*132 + c4*8);
        const float w1 = a*uv.x, w2 = a*uv.y;
        const float wv[6] = {a, w1, w2, w1*uv.x, 2.0f*w1*uv.y, w2*uv.y};
        #pragma unroll
        for (int p = 0; p < 6; ++p)
            #pragma unroll
            for (int j = 0; j < 8; ++j) G[p][j] += wv[p] * fv[j];
    }
    __syncthreads();                  // F dead; HEAD may overwrite

    float hd[8];
    #pragma unroll
    for (int i = 0; i < 8; ++i) hd[i] = 0.f;
    #pragma unroll
    for (int p = 0; p < 6; ++p) {
        #pragma unroll
        for (int i = 0; i < 8; ++i) {
            const float4 a0 = *(const float4*)&A4[(((p*8+i)*64 + hc)*8)];
            const float4 a1 = *(const float4*)&A4[(((p*8+i)*64 + hc)*8) + 4];
            hd[i] += a0.x*G[p][0] + a0.y*G[p][1] + a0.z*G[p][2] + a0.w*G[p][3]
                   + a1.x*G[p][4] + a1.y*G[p][5] + a1.z*G[p][6] + a1.w*G[p][7];
        }
    }
    ST8(OFF_HEAD + v4*520 + hc*8, hd);
    __syncthreads();

    // ---- P5: projection (wm from L1, rotation-in-registers) ----
    {
        const int v = tid >> 6, o = (tid >> 2) & 15, cs = tid & 3;
        float acc[8] = {0,0,0,0,0,0,0,0};
        #pragma unroll 2
        for (int cc = 0; cc < 16; ++cc) {
            const int cp = cc*4 + cs;
            float hh[8]; LD8(hh, OFF_HEAD + v*520 + cp*8);
            const float4 w0 = *(const float4*)&wm[(o*64 + cp)*8];
            const float4 w1 = *(const float4*)&wm[(o*64 + cp)*8 + 4];
            float wv[8] = {w0.x,w0.y,w0.z,w0.w,w1.x,w1.y,w1.z,w1.w};
            #pragma unroll
            for (int d = 0; d < 8; ++d)
                #pragma unroll
                for (int i = 0; i < 8; ++i)
                    acc[i] += wv[d] * hh[(i+d)&7];
        }
        #pragma unroll
        for (int i = 0; i < 8; ++i) {
            acc[i] += __shfl_xor(acc[i], 1, 64);
            acc[i] += __shfl_xor(acc[i], 2, 64);
        }
        if (cs == 0) {
            float* op = out + (size_t)(vbase + v)*128 + o*8;
            *(float4*)op       = make_float4(acc[0],acc[1],acc[2],acc[3]);
            *(float4*)(op + 4) = make_float4(acc[4],acc[5],acc[6],acc[7]);
        }
    }
}

extern "C" void kernel_launch(void* const* d_in, const int* in_sizes, int n_in,
                              void* d_out, int out_size, void* d_ws, size_t ws_size,
                              hipStream_t stream)
{
    const float* x   = (const float*)d_in[0];
    const int*   nbr = (const int*)d_in[1];
    const unsigned char* msk = (const unsigned char*)d_in[2];
    const float* pt  = (const float*)d_in[3];
    const float* rel = (const float*)d_in[4];
    // d_in[5] reg_basis: circulant structure exploited analytically
    const float* vb1 = (const float*)d_in[6];
    const float* vb2 = (const float*)d_in[7];
    const float* qc  = (const float*)d_in[8];
    const float* kc  = (const float*)d_in[9];
    const float* v0p = (const float*)d_in[10];
    const float* v1p = (const float*)d_in[11];
    const float* v2p = (const float*)d_in[12];
    const float* wm  = (const float*)d_in[13];

    int*   flag = (int*)d_ws;
    float* A4   = (float*)d_ws + 64;
    float* outp = (float*)d_out;

    hipLaunchKernelGGL(kprep, dim3(97),   dim3(256), 0, stream,
                       v0p, v1p, v2p, vb1, vb2, A4, msk, flag);
    hipLaunchKernelGGL(kmain, dim3(GRID), dim3(256), 0, stream,
                       x, nbr, msk, pt, rel, qc, kc, A4, wm, flag, outp);
}